// Round 2
// baseline (365.481 us; speedup 1.0000x reference)
//
#include <hip/hip_runtime.h>

// Problem: h_t = f_t*x_t + (1-f_t)*h_{t-1}, SEQ=1024, B*H=32768 channels, fp32.
// Layout [t][channel], channel fastest.
//
// Round-3: two-pass chunked scan (recurrence is affine in h: over a chunk,
// h_out = A*h_in + B with A = prod(1-f), B = zero-init scan).
// Round-2 lesson: occupancy fixed (30%) but scalar 4B/lane loads capped
// effective BW at ~2.5 TB/s (fm_sum: 224MB in 90us). The 6.3 TB/s ceiling
// needs 16B/lane (m13: float4 copy). So: 4 channels per thread -> dwordx4
// loads/stores, NCHUNK 8->16 to keep wave count up (pass2: 8 waves/CU).
// Non-temporal stores for the 128MB 'out' stream so it doesn't evict f,x
// from L3 between the passes.

typedef float f4 __attribute__((ext_vector_type(4)));

#define SEQ 1024
#define NCH 32768            // B*H channels
#define NCHUNK 16
#define CLEN (SEQ / NCHUNK)  // 64 timesteps per chunk
#define TPB 256
#define CHPB (TPB * 4)       // 1024 channels per block (4 per thread)
#define S4 (NCH / 4)         // timestep stride in f4 units = 8192
#define UNR 4                // timesteps per prefetch buffer (4 x f4 x 2 arrays x 2 bufs = 64 VGPR)

// Pass 1: per-chunk affine summaries (A,B) for chunks 0..NCHUNK-2.
// grid (32, 15) = 480 blocks * 4 waves = 7.5 waves/CU.
__global__ __launch_bounds__(TPB) void fm_sum(const float* __restrict__ f,
                                              const float* __restrict__ x,
                                              float* __restrict__ Aw,
                                              float* __restrict__ Bw) {
    const int c = blockIdx.y;
    const int ch4 = blockIdx.x * TPB + threadIdx.x;      // float4-group index
    const size_t base = (size_t)c * CLEN * S4 + ch4;
    const f4* fp = (const f4*)f + base;
    const f4* xp = (const f4*)x + base;

    f4 A = {1.f, 1.f, 1.f, 1.f};
    f4 Bv = {0.f, 0.f, 0.f, 0.f};
    f4 fA[UNR], xA[UNR], fB[UNR], xB[UNR];

#pragma unroll
    for (int j = 0; j < UNR; ++j) {
        fA[j] = fp[(size_t)j * S4];
        xA[j] = xp[(size_t)j * S4];
    }

    for (int t0 = 0; t0 < CLEN; t0 += 2 * UNR) {
#pragma unroll
        for (int j = 0; j < UNR; ++j) {
            fB[j] = fp[(size_t)(t0 + UNR + j) * S4];
            xB[j] = xp[(size_t)(t0 + UNR + j) * S4];
        }
#pragma unroll
        for (int j = 0; j < UNR; ++j) {
            Bv = fA[j] * (xA[j] - Bv) + Bv;   // B' = f*x + (1-f)*B
            A  = A - fA[j] * A;               // A' = (1-f)*A
        }
        if (t0 + 2 * UNR < CLEN) {
#pragma unroll
            for (int j = 0; j < UNR; ++j) {
                fA[j] = fp[(size_t)(t0 + 2 * UNR + j) * S4];
                xA[j] = xp[(size_t)(t0 + 2 * UNR + j) * S4];
            }
        }
#pragma unroll
        for (int j = 0; j < UNR; ++j) {
            Bv = fB[j] * (xB[j] - Bv) + Bv;
            A  = A - fB[j] * A;
        }
    }

    __builtin_nontemporal_store(A,  (f4*)Aw + (size_t)c * S4 + ch4);
    __builtin_nontemporal_store(Bv, (f4*)Bw + (size_t)c * S4 + ch4);
}

// Pass 2: compose h_start from h0 + summaries of chunks < c, then scan CLEN steps.
// grid (32, 16) = 512 blocks * 4 waves = 8 waves/CU.
__global__ __launch_bounds__(TPB) void fm_scan(const float* __restrict__ f,
                                               const float* __restrict__ x,
                                               const float* __restrict__ h0,
                                               const float* __restrict__ Aw,
                                               const float* __restrict__ Bw,
                                               float* __restrict__ out) {
    const int c = blockIdx.y;
    const int ch4 = blockIdx.x * TPB + threadIdx.x;
    const size_t base = (size_t)c * CLEN * S4 + ch4;
    const f4* fp = (const f4*)f + base;
    const f4* xp = (const f4*)x + base;
    f4* op = (f4*)out + base;

    f4 h = ((const f4*)h0)[ch4];
    for (int k = 0; k < c; ++k) {   // <= 15 affine composes, summaries are L2/L3-hot
        f4 a = ((const f4*)Aw)[(size_t)k * S4 + ch4];
        f4 b = ((const f4*)Bw)[(size_t)k * S4 + ch4];
        h = a * h + b;
    }

    f4 fA[UNR], xA[UNR], fB[UNR], xB[UNR];
#pragma unroll
    for (int j = 0; j < UNR; ++j) {
        fA[j] = fp[(size_t)j * S4];
        xA[j] = xp[(size_t)j * S4];
    }

    for (int t0 = 0; t0 < CLEN; t0 += 2 * UNR) {
#pragma unroll
        for (int j = 0; j < UNR; ++j) {
            fB[j] = fp[(size_t)(t0 + UNR + j) * S4];
            xB[j] = xp[(size_t)(t0 + UNR + j) * S4];
        }
#pragma unroll
        for (int j = 0; j < UNR; ++j) {
            h = fA[j] * (xA[j] - h) + h;      // h = f*x + (1-f)*h
            __builtin_nontemporal_store(h, op + (size_t)(t0 + j) * S4);
        }
        if (t0 + 2 * UNR < CLEN) {
#pragma unroll
            for (int j = 0; j < UNR; ++j) {
                fA[j] = fp[(size_t)(t0 + 2 * UNR + j) * S4];
                xA[j] = xp[(size_t)(t0 + 2 * UNR + j) * S4];
            }
        }
#pragma unroll
        for (int j = 0; j < UNR; ++j) {
            h = fB[j] * (xB[j] - h) + h;
            __builtin_nontemporal_store(h, op + (size_t)(t0 + UNR + j) * S4);
        }
    }
}

extern "C" void kernel_launch(void* const* d_in, const int* in_sizes, int n_in,
                              void* d_out, int out_size, void* d_ws, size_t ws_size,
                              hipStream_t stream) {
    const float* f  = (const float*)d_in[0];
    const float* x  = (const float*)d_in[1];
    const float* h0 = (const float*)d_in[2];
    float* out = (float*)d_out;

    // Workspace: (NCHUNK-1)*NCH floats for A and for B -> 3.94 MB total.
    float* Aw = (float*)d_ws;
    float* Bw = Aw + (size_t)(NCHUNK - 1) * NCH;

    fm_sum<<<dim3(NCH / CHPB, NCHUNK - 1), dim3(TPB), 0, stream>>>(f, x, Aw, Bw);
    fm_scan<<<dim3(NCH / CHPB, NCHUNK), dim3(TPB), 0, stream>>>(f, x, h0, Aw, Bw, out);
}

// Round 3
// 344.854 us; speedup vs baseline: 1.0598x; 1.0598x over previous
//
#include <hip/hip_runtime.h>

// h_t = f_t*x_t + (1-f_t)*h_{t-1}, SEQ=1024, B*H=32768 channels, fp32,
// layout [t][channel] (channel fastest).
//
// Round-4: SINGLE-PASS fused block scan. Rounds 1-3 lesson: effective BW is
// queue-limited at ~1.7 TB/s cold / ~2.2-3.3 TB/s warm for this access
// pattern no matter the vector width or wave count, so total HBM traffic is
// the dominant cost. The two-pass summary approach paid +65% traffic
// (630 MB vs 384 MB ideal) and regressed. This version reads f,x ONCE and
// writes out ONCE (384 MB total, the ideal):
//
//   block = 1024 threads = 128 time-chunks x 8 f4-channel-groups.
//   Each thread scans CLEN=8 steps of 4 channels with h_in = 0, stashing
//   per-step (partial_h, prefix_A) in registers:
//       ph_t = f*x + (1-f)*ph_{t-1}   (zero-init partial scan)
//       aP_t = (1-f)*aP_{t-1}         (decay product)
//   so the true h_t = ph_t + aP_t * h_start  for any h_start.
//   Chunk summaries (A,B) = (aP_7, ph_7) go through a block-wide
//   Hillis-Steele scan in LDS (7 rounds), giving each chunk its h_start
//   composed from h0 -- no workspace traffic, no second pass.

typedef float f4 __attribute__((ext_vector_type(4)));

#define SEQ 1024
#define NCH 32768
#define S4 (NCH / 4)        // 8192 f4 per timestep row
#define CLEN 8              // timesteps per thread
#define NCHUNK (SEQ / CLEN) // 128 chunks = full time axis per block
#define CGPB 8              // f4 channel-groups per block (32 channels)
#define TPB (NCHUNK * CGPB) // 1024 threads

__global__ __launch_bounds__(TPB) void fm_fused(const float* __restrict__ f,
                                                const float* __restrict__ x,
                                                const float* __restrict__ h0,
                                                float* __restrict__ out) {
    const int tid = threadIdx.x;
    const int cg = tid & (CGPB - 1);      // channel-group within block
    const int c  = tid >> 3;              // time-chunk 0..127
    const int ch4 = blockIdx.x * CGPB + cg;  // global f4 channel index
    const size_t base = (size_t)c * CLEN * S4 + ch4;
    const f4* fp = (const f4*)f + base;
    const f4* xp = (const f4*)x + base;
    f4* op = (f4*)out + base;

    // h0 load issued early to overlap with the bulk loads.
    const f4 h0v = ((const f4*)h0)[ch4];

    // Load this thread's 8 timesteps of f and x (16 dwordx4 in flight).
    f4 fv[CLEN], xv[CLEN];
#pragma unroll
    for (int j = 0; j < CLEN; ++j) {
        fv[j] = fp[(size_t)j * S4];
        xv[j] = xp[(size_t)j * S4];
    }

    // Zero-init partial scan; stash per-step (prefix_A, partial_h) in place.
    f4 ph = {0.f, 0.f, 0.f, 0.f};
    f4 aP = {1.f, 1.f, 1.f, 1.f};
#pragma unroll
    for (int j = 0; j < CLEN; ++j) {
        ph = fv[j] * (xv[j] - ph) + ph;  // ph = f*x + (1-f)*ph
        aP = aP - fv[j] * aP;            // aP *= (1-f)
        fv[j] = aP;                      // stash prefix_A after step j
        xv[j] = ph;                      // stash partial_h after step j
    }

    // Block-wide inclusive scan of chunk summaries along the chunk axis.
    // Composition (apply older then newer): A <- A*ap, B <- B + A*bp.
    __shared__ f4 As[NCHUNK][CGPB];
    __shared__ f4 Bs[NCHUNK][CGPB];
    As[c][cg] = aP;
    Bs[c][cg] = ph;
    __syncthreads();

    f4 Ac = aP, Bc = ph;
#pragma unroll
    for (int off = 1; off < NCHUNK; off <<= 1) {
        f4 ap, bp;
        const bool act = (c >= off);
        if (act) {
            ap = As[c - off][cg];
            bp = Bs[c - off][cg];
        }
        __syncthreads();
        if (act) {
            Bc = Bc + Ac * bp;
            Ac = Ac * ap;
            As[c][cg] = Ac;
            Bs[c][cg] = Bc;
        }
        __syncthreads();
    }

    // Exclusive prefix -> h_start for this chunk, applied to h0.
    f4 hs;
    if (c == 0) {
        hs = h0v;
    } else {
        hs = Bs[c - 1][cg] + As[c - 1][cg] * h0v;
    }

    // Final outputs from stashed registers: h_t = ph_t + aP_t * h_start.
#pragma unroll
    for (int j = 0; j < CLEN; ++j) {
        f4 h = xv[j] + fv[j] * hs;
        __builtin_nontemporal_store(h, op + (size_t)j * S4);
    }
}

extern "C" void kernel_launch(void* const* d_in, const int* in_sizes, int n_in,
                              void* d_out, int out_size, void* d_ws, size_t ws_size,
                              hipStream_t stream) {
    const float* f  = (const float*)d_in[0];
    const float* x  = (const float*)d_in[1];
    const float* h0 = (const float*)d_in[2];
    float* out = (float*)d_out;

    // 8192 f4 channel-groups / 8 per block = 1024 blocks of 1024 threads.
    fm_fused<<<dim3(S4 / CGPB), dim3(TPB), 0, stream>>>(f, x, h0, out);
}